// Round 9
// baseline (315.125 us; speedup 1.0000x reference)
//
#include <hip/hip_runtime.h>

// ---------------------------------------------------------------------------
// SpatialTransformer attention, dtype-robust (fp32 vs bf16 storage detect).
// Round 11: LDS bank-conflict fix on the 128x128 core, schedule UNTOUCHED.
// The old [KU][128][32] tile (64B row stride) put ds_read_b128 fragment
// reads at 8-way bank conflict (SQ_LDS_BANK_CONFLICT = 6.29M/dispatch, all
// session).  Transplant the round-6-verified layout (conflicts measured 0):
// one [128][64] tile per operand (128B row stride = full bank coverage),
// 16B chunk (row, ch) stored at position ch ^ (row&7) via pre-swizzled
// GLOBAL source (linear global_load_lds dest, rule #21); reads use
// chk_u = ((4u+quad) ^ (lrow&7))*8.  2-barrier loop, 8 loads/thread/K-tile,
// MFMA order, epilogues, grids: all identical to round-10 (314.7us).
// Pipeline: convert(+detect+denom-zero) -> QKV(+Q-scale, V^T) ->
// PEXP(exp, denom atomics) -> RES(PV/denom + residual) -> OUT.  5 dispatches.
// ---------------------------------------------------------------------------

typedef __attribute__((ext_vector_type(8))) short short8;
typedef __attribute__((ext_vector_type(8))) unsigned short ushort8;
typedef __attribute__((ext_vector_type(4))) unsigned short ushort4v;
typedef __attribute__((ext_vector_type(4))) float f32x4;

__device__ __forceinline__ float b2f(unsigned short u) {
  union { unsigned int i; float f; } x;
  x.i = ((unsigned int)u) << 16;
  return x.f;
}
__device__ __forceinline__ unsigned short f2b(float f) {
  union { float f; unsigned int i; } x;
  x.f = f;
  unsigned int i = x.i;
  i += 0x7fffu + ((i >> 16) & 1u);  // RNE
  return (unsigned short)(i >> 16);
}

__device__ __forceinline__ void async_copy16(const void* g, void* l) {
  __builtin_amdgcn_global_load_lds(
      (const __attribute__((address_space(1))) unsigned int*)g,
      (__attribute__((address_space(3))) unsigned int*)l, 16, 0, 0);
}

// --- one fused conversion of all 10 inputs into a contiguous bf16 concat.
// Also: per-block storage-format self-detection (fp32 storage => even
// ushorts are mantissa bits, exponent-like field saturates); block 0
// publishes the flag for the OUT kernel; blocks 0-31 zero the denominator.
struct CvtArgs { const void* src[10]; };

__global__ __launch_bounds__(256) void convert_all(
    CvtArgs a, unsigned short* __restrict__ dst, int* __restrict__ flag,
    float* __restrict__ dn) {
  // self-detect (identical sampling to the old detect_fmt kernel)
  const unsigned short* xr = (const unsigned short*)a.src[0];
  int c = 0;
  for (int i = threadIdx.x * 2; i < 8192; i += 512) {
    unsigned e = (xr[i] >> 7) & 0xFF;
    if (e >= 0x90) ++c;
  }
#pragma unroll
  for (int off = 32; off > 0; off >>= 1) c += __shfl_xor(c, off);
  __shared__ int redc[4];
  if ((threadIdx.x & 63) == 0) redc[threadIdx.x >> 6] = c;
  __syncthreads();
  const int total = redc[0] + redc[1] + redc[2] + redc[3];
  const bool f32 = total > 64;
  if (blockIdx.x == 0 && threadIdx.x == 0) *flag = f32 ? 1 : 0;
  if (blockIdx.x < 32) dn[blockIdx.x * 256 + threadIdx.x] = 0.f;

  const long nchunk = 2621952;  // 20975616 / 8
  for (long cc = blockIdx.x * 256L + threadIdx.x; cc < nchunk;
       cc += 2048L * 256) {
    const long flat = cc * 8;
    int t; long off;
    if      (flat < 8388608)  { t = 0; off = 0; }
    else if (flat < 16777216) { t = 1; off = 8388608; }
    else if (flat < 17825792) { t = 2; off = 16777216; }
    else if (flat < 17826816) { t = 3; off = 17825792; }
    else if (flat < 18875392) { t = 4; off = 17826816; }
    else if (flat < 18876416) { t = 5; off = 18875392; }
    else if (flat < 19924992) { t = 6; off = 18876416; }
    else if (flat < 19926016) { t = 7; off = 19924992; }
    else if (flat < 20974592) { t = 8; off = 19926016; }
    else                      { t = 9; off = 20974592; }
    const long li = flat - off;
    if (f32) {
      const float* s = (const float*)a.src[t] + li;
      const f32x4 lo = *(const f32x4*)s;
      const f32x4 hi = *(const f32x4*)(s + 4);
      ushort8 o;
      o[0] = f2b(lo[0]); o[1] = f2b(lo[1]); o[2] = f2b(lo[2]); o[3] = f2b(lo[3]);
      o[4] = f2b(hi[0]); o[5] = f2b(hi[1]); o[6] = f2b(hi[2]); o[7] = f2b(hi[3]);
      *(ushort8*)(dst + flat) = o;
    } else {
      *(ushort8*)(dst + flat) =
          *(const ushort8*)((const unsigned short*)a.src[t] + li);
    }
  }
}

#define MODE_BIAS 0  // bf16 out = (acc + bias[n])*scale  (vt: V^T store)
#define MODE_RES  2  // bf16 out = acc/denom[row] + res[m,n]
#define MODE_OUT  4  // format-aware out = acc + bias[n]  (fp32 or bf16 store)
#define MODE_PEXP 5  // bf16 out = exp(acc*scale); denom[row] += row-sum

// XCD-band swizzle: round-robin XCD = linear%8 (assumed); blocks sharing a
// logical `by` (same A row-tile) land on one XCD, bx sweeping 0..gx.
// Requires gy % 8 == 0 (true for all our grids).
__device__ __forceinline__ void xcd_swizzle(int gx, int gy, int& bx, int& by) {
  const int L = blockIdx.y * gx + blockIdx.x;
  const int r = L & 7, m = L >> 3;
  bx = m % gx;
  by = r * (gy >> 3) + m / gx;
}

// ===========================================================================
// 128x128 core, BK=64 per barrier (= old KU=2), 4 waves (2x2) of 64x64,
// fp32 accum, global_load_lds width=16 staging, mfma_f32_16x16x32_bf16.
// LDS: As/Bs = [128 rows][64 cols] bf16 (128B row stride, 16KB each).
// Swizzle (round-6 verified, conflicts=0): chunk (row, ch) stored at
// position ch ^ (row&7); staging pre-swizzles the GLOBAL source chunk
// (LDS dest stays linear: thread tid -> bytes tid*16 + issue*4096);
// fragment reads use chk_u = ((4u+quad) ^ (lrow&7))*8 (row&7 == lrow&7
// for all fragment rows since 64 and 16 are multiples of 8).
// vt (MODE_BIAS only): store transposed to C as Vt[b][col][kv].
// ===========================================================================
template <int MODE>
__device__ __forceinline__ void gemm_core(
    const unsigned short* __restrict__ A, const unsigned short* __restrict__ B,
    void* __restrict__ C, const unsigned short* __restrict__ bias,
    const unsigned short* __restrict__ Res, const int* __restrict__ flg,
    float* __restrict__ dn, int N, int K, float scale, int bx, int by,
    int vt) {
  __shared__ __align__(16) unsigned short As[128 * 64];
  __shared__ __align__(16) unsigned short Bs[128 * 64];
  const int tid = threadIdx.x;
  const int wave = tid >> 6, lane = tid & 63;
  const int wm = wave >> 1, wn = wave & 1;
  const int quad = lane >> 4, lrow = lane & 15;

  // staging map: thread tid covers linear LDS bytes tid*16 (+4096/issue);
  // logical source chunk is pre-swizzled (involution ch ^ (row&7)).
  const int srow = tid >> 3;                    // 0..31 (issue-0 row)
  const int sch = (tid & 7) ^ (srow & 7);       // swizzled source chunk
  const unsigned short* ag = A + (long)(by * 128 + srow) * K + sch * 8;
  const unsigned short* bg = B + (long)(bx * 128 + srow) * K + sch * 8;
  char* const lA = (char*)As + tid * 16;
  char* const lB = (char*)Bs + tid * 16;

  f32x4 acc[4][4];
#pragma unroll
  for (int i = 0; i < 4; ++i)
#pragma unroll
    for (int j = 0; j < 4; ++j) acc[i][j] = (f32x4){0.f, 0.f, 0.f, 0.f};

  for (int kt = 0; kt < K; kt += 64) {
#pragma unroll
    for (int s = 0; s < 4; ++s) {   // 4 issues x 32 rows = 128 rows
      async_copy16(ag + kt + (long)32 * s * K, lA + s * 4096);
      async_copy16(bg + kt + (long)32 * s * K, lB + s * 4096);
    }
    __syncthreads();
#pragma unroll
    for (int u = 0; u < 2; ++u) {
      const int chk = ((4 * u + quad) ^ (lrow & 7)) * 8;
      short8 af[4], bfr[4];
#pragma unroll
      for (int i = 0; i < 4; ++i)
        af[i] = *(const short8*)(As + (wm * 64 + i * 16 + lrow) * 64 + chk);
#pragma unroll
      for (int j = 0; j < 4; ++j)
        bfr[j] = *(const short8*)(Bs + (wn * 64 + j * 16 + lrow) * 64 + chk);
#pragma unroll
      for (int i = 0; i < 4; ++i)
#pragma unroll
        for (int j = 0; j < 4; ++j)
          acc[i][j] = __builtin_amdgcn_mfma_f32_16x16x32_bf16(
              af[i], bfr[j], acc[i][j], 0, 0, 0);
    }
    __syncthreads();
  }

  // C/D layout: col=lane&15, row=(lane>>4)*4+reg (m89-verified)

  if (MODE == MODE_PEXP) {
    // store P = bf16(exp(acc*scale)) and accumulate per-row sums of the
    // ROUNDED p into dn[row] (what PV will actually consume).
#pragma unroll
    for (int i = 0; i < 4; ++i) {
      const long row = (long)by * 128 + wm * 64 + i * 16 + quad * 4;
#pragma unroll
      for (int r = 0; r < 4; ++r) {
        float rs = 0.f;
#pragma unroll
        for (int j = 0; j < 4; ++j) {
          const long col = (long)bx * 128 + wn * 64 + j * 16 + lrow;
          const unsigned short pb = f2b(__expf(acc[i][j][r] * scale));
          ((unsigned short*)C)[(row + r) * N + col] = pb;
          rs += b2f(pb);
        }
        rs += __shfl_xor(rs, 1);
        rs += __shfl_xor(rs, 2);
        rs += __shfl_xor(rs, 4);
        rs += __shfl_xor(rs, 8);
        if (lrow == 0) atomicAdd(&dn[row + r], rs);
      }
    }
    return;
  }

  const bool f32out = (MODE == MODE_OUT) ? (*flg != 0) : false;
#pragma unroll
  for (int i = 0; i < 4; ++i) {
    const long row = (long)by * 128 + wm * 64 + i * 16 + quad * 4;
    float invd[4];
    if (MODE == MODE_RES) {
#pragma unroll
      for (int r = 0; r < 4; ++r) invd[r] = 1.0f / dn[row + r];
    }
#pragma unroll
    for (int j = 0; j < 4; ++j) {
      const long col = (long)bx * 128 + wn * 64 + j * 16 + lrow;
      if (MODE == MODE_BIAS && vt) {
        // V^T store: Vt[b][col][kv], 4 consecutive rows -> one 8B store
        const float bb = b2f(bias[col]);
        ushort4v pk;
#pragma unroll
        for (int r = 0; r < 4; ++r) pk[r] = f2b((acc[i][j][r] + bb) * scale);
        const long b = row >> 11, kvr = row & 2047;
        *(ushort4v*)((unsigned short*)C + b * 2097152 + col * 2048 + kvr) = pk;
        continue;
      }
#pragma unroll
      for (int r = 0; r < 4; ++r) {
        const float v = acc[i][j][r];
        const long idx = (row + r) * N + col;
        if (MODE == MODE_BIAS) {
          ((unsigned short*)C)[idx] = f2b((v + b2f(bias[col])) * scale);
        } else if (MODE == MODE_RES) {
          ((unsigned short*)C)[idx] = f2b(v * invd[r] + b2f(Res[idx]));
        } else {  // MODE_OUT
          const float o = v + b2f(bias[col]);
          if (f32out) ((float*)C)[idx] = o;
          else        ((unsigned short*)C)[idx] = f2b(o);
        }
      }
    }
  }
}

template <int MODE>
__global__ __launch_bounds__(256, 2) void gemm_nt(
    const unsigned short* __restrict__ A, const unsigned short* __restrict__ B,
    void* __restrict__ C, const unsigned short* __restrict__ bias,
    const unsigned short* __restrict__ Res, const int* __restrict__ flg,
    float* __restrict__ dn, int N, int K, float scale, long sA, long sB,
    long sC, long sR, int vt) {
  const int bz = blockIdx.z;
  int bx, by;
  xcd_swizzle(gridDim.x, gridDim.y, bx, by);
  const unsigned short* Rb = (MODE == MODE_RES) ? Res + bz * sR : nullptr;
  float* dnb = (MODE == MODE_RES || MODE == MODE_PEXP) ? dn + bz * 2048
                                                       : nullptr;
  void* Cb = (MODE == MODE_OUT) ? (void*)((char*)C)
                                : (void*)((unsigned short*)C + bz * sC);
  gemm_core<MODE>(A + bz * sA, B + bz * sB, Cb, bias, Rb, flg, dnb, N, K,
                  scale, bx, by, vt);
}

// merged Q/K/V projections: blockIdx.z selects (A,B,C,bias); z==0 (Q)
// carries the softmax scale (2^-5, exact exponent shift -> S bit-identical);
// z==2 (V) stores transposed into the Vt buffer.
struct QkvArgs {
  const unsigned short* A[3];
  const unsigned short* B[3];
  unsigned short* C[3];
  const unsigned short* bias[3];
};
__global__ __launch_bounds__(256, 2) void gemm_qkv(QkvArgs a, int N, int K,
                                                   float qscale) {
  const int z = blockIdx.z;
  int bx, by;
  xcd_swizzle(gridDim.x, gridDim.y, bx, by);
  gemm_core<MODE_BIAS>(a.A[z], a.B[z], a.C[z], a.bias[z], nullptr, nullptr,
                       nullptr, N, K, z == 0 ? qscale : 1.f, bx, by,
                       z == 2 ? 1 : 0);
}

extern "C" void kernel_launch(void* const* d_in, const int* in_sizes, int n_in,
                              void* d_out, int out_size, void* d_ws,
                              size_t ws_size, hipStream_t stream) {
  char* ws = (char*)d_ws;
  const long MB = 1 << 20;
  unsigned short* C0  = (unsigned short*)ws;  // bf16 concat of inputs
  unsigned short* xb  = C0;
  unsigned short* ceb = C0 + 8388608;
  unsigned short* Wqb = C0 + 16777216;
  unsigned short* bqb = C0 + 17825792;
  unsigned short* Wkb = C0 + 17826816;
  unsigned short* bkb = C0 + 18875392;
  unsigned short* Wvb = C0 + 18876416;
  unsigned short* bvb = C0 + 19924992;
  unsigned short* Wob = C0 + 19926016;
  unsigned short* bob = C0 + 20974592;
  int*            flg = (int*)(ws + 41 * MB);
  unsigned short* Q   = (unsigned short*)(ws + 42 * MB);  // 42-58
  unsigned short* Kp  = (unsigned short*)(ws + 58 * MB);  // 58-74
  unsigned short* Vt  = (unsigned short*)(ws + 74 * MB);  // 74-90 (V^T direct)
  unsigned short* S   = (unsigned short*)(ws + 90 * MB);  // 90-122 (->P=exp)
  float*          dnm = (float*)(ws + 122 * MB);          // 4x2048 f32 denom
  unsigned short* Ar  = Kp;  // reuse K slot after QK^T

  const dim3 blk(256);
  const float scale = 0.03125f;  // 1/sqrt(1024) = 2^-5 (exact in bf16 mul)

  // convert + self-detect + flag publish + denom zero (one dispatch)
  CvtArgs ca;
  for (int i = 0; i < 10; ++i) ca.src[i] = d_in[i];
  convert_all<<<dim3(2048), blk, 0, stream>>>(ca, C0, flg, dnm);

  // merged QKV projections: M=8192 (batch folded), N=K=1024; Q carries the
  // softmax scale; V transposed into Vt ([b][1024][2048]).  Grid 8x64x3.
  QkvArgs qa;
  qa.A[0] = xb;  qa.A[1] = ceb; qa.A[2] = ceb;
  qa.B[0] = Wqb; qa.B[1] = Wkb; qa.B[2] = Wvb;
  qa.C[0] = Q;   qa.C[1] = Kp;  qa.C[2] = Vt;
  qa.bias[0] = bqb; qa.bias[1] = bkb; qa.bias[2] = bvb;
  gemm_qkv<<<dim3(8, 64, 3), blk, 0, stream>>>(qa, 1024, 1024, scale);

  // P = exp(QK^T) unnormalized (bf16; scale already in Q) + per-row denom
  // accumulation; per batch 2048x2048, K=1024.
  gemm_nt<MODE_PEXP><<<dim3(16, 16, 4), blk, 0, stream>>>(
      Q, Kp, S, nullptr, nullptr, nullptr, dnm, 2048, 1024, 1.f,
      2048L * 1024, 2048L * 1024, 2048L * 2048, 0, 0);

  // A = x + (P@V)/denom : per batch M=2048, N=1024, K=2048 (B=Vt, NT)
  gemm_nt<MODE_RES><<<dim3(8, 16, 4), blk, 0, stream>>>(
      S, Vt, Ar, nullptr, xb, nullptr, dnm, 1024, 2048, 1.f,
      2048L * 2048, 1024L * 2048, 2048L * 1024, 2048L * 1024, 0);

  // out = A@Wo^T + bo, written straight to d_out in detected format
  gemm_nt<MODE_OUT><<<dim3(8, 64, 1), blk, 0, stream>>>(
      Ar, Wob, d_out, bob, nullptr, flg, nullptr, 1024, 1024, 1.f,
      0, 0, 0, 0, 0);
}

// Round 10
// 305.679 us; speedup vs baseline: 1.0309x; 1.0309x over previous
//
#include <hip/hip_runtime.h>

// ---------------------------------------------------------------------------
// SpatialTransformer attention, dtype-robust (fp32 vs bf16 storage detect).
// Round 12: occupancy-hint round.  Round-11 verified: bank conflicts 6.29M->0,
// QKV 65.5->59.8us @ 861 TF = the m97-structure ceiling; but OccupancyPercent
// sits at 31% (~2.5 blocks/CU) while LDS (32KB -> 5 blocks/CU) and VGPR (64)
// would allow 5.  Changes vs round-11 (both zero-correctness-risk):
//  (1) __launch_bounds__(256, 4) on all GEMM kernels (was (256,2)) — 64 VGPR
//      fits 4 waves/EU with 2x headroom; more co-resident blocks = cross-
//      block MFMA/staging overlap (m114 mechanism), the only remaining lever
//      on MfmaUtil without a schedule rewrite (both 256^2 rewrites lost).
//  (2) MODE_PEXP epilogue uses __expf(acc) directly (scale is baked into Q
//      since round 10; the runtime 1.f arg still emitted 64 v_muls/thread).
// Pipeline (5 dispatches): convert(+detect+denom-zero) -> QKV(+Q-scale, V^T)
// -> PEXP(exp + denom atomics) -> RES(PV/denom + residual) -> OUT.
// Core: 128x128, BK=64, [128][64] LDS tiles, ch^(row&7) swizzle both sides
// (conflicts=0 verified), global_load_lds w=16, mfma_f32_16x16x32_bf16.
// ---------------------------------------------------------------------------

typedef __attribute__((ext_vector_type(8))) short short8;
typedef __attribute__((ext_vector_type(8))) unsigned short ushort8;
typedef __attribute__((ext_vector_type(4))) unsigned short ushort4v;
typedef __attribute__((ext_vector_type(4))) float f32x4;

__device__ __forceinline__ float b2f(unsigned short u) {
  union { unsigned int i; float f; } x;
  x.i = ((unsigned int)u) << 16;
  return x.f;
}
__device__ __forceinline__ unsigned short f2b(float f) {
  union { float f; unsigned int i; } x;
  x.f = f;
  unsigned int i = x.i;
  i += 0x7fffu + ((i >> 16) & 1u);  // RNE
  return (unsigned short)(i >> 16);
}

__device__ __forceinline__ void async_copy16(const void* g, void* l) {
  __builtin_amdgcn_global_load_lds(
      (const __attribute__((address_space(1))) unsigned int*)g,
      (__attribute__((address_space(3))) unsigned int*)l, 16, 0, 0);
}

// --- one fused conversion of all 10 inputs into a contiguous bf16 concat.
// Also: per-block storage-format self-detection (fp32 storage => even
// ushorts are mantissa bits, exponent-like field saturates); block 0
// publishes the flag for the OUT kernel; blocks 0-31 zero the denominator.
struct CvtArgs { const void* src[10]; };

__global__ __launch_bounds__(256) void convert_all(
    CvtArgs a, unsigned short* __restrict__ dst, int* __restrict__ flag,
    float* __restrict__ dn) {
  // self-detect (identical sampling to the old detect_fmt kernel)
  const unsigned short* xr = (const unsigned short*)a.src[0];
  int c = 0;
  for (int i = threadIdx.x * 2; i < 8192; i += 512) {
    unsigned e = (xr[i] >> 7) & 0xFF;
    if (e >= 0x90) ++c;
  }
#pragma unroll
  for (int off = 32; off > 0; off >>= 1) c += __shfl_xor(c, off);
  __shared__ int redc[4];
  if ((threadIdx.x & 63) == 0) redc[threadIdx.x >> 6] = c;
  __syncthreads();
  const int total = redc[0] + redc[1] + redc[2] + redc[3];
  const bool f32 = total > 64;
  if (blockIdx.x == 0 && threadIdx.x == 0) *flag = f32 ? 1 : 0;
  if (blockIdx.x < 32) dn[blockIdx.x * 256 + threadIdx.x] = 0.f;

  const long nchunk = 2621952;  // 20975616 / 8
  for (long cc = blockIdx.x * 256L + threadIdx.x; cc < nchunk;
       cc += 2048L * 256) {
    const long flat = cc * 8;
    int t; long off;
    if      (flat < 8388608)  { t = 0; off = 0; }
    else if (flat < 16777216) { t = 1; off = 8388608; }
    else if (flat < 17825792) { t = 2; off = 16777216; }
    else if (flat < 17826816) { t = 3; off = 17825792; }
    else if (flat < 18875392) { t = 4; off = 17826816; }
    else if (flat < 18876416) { t = 5; off = 18875392; }
    else if (flat < 19924992) { t = 6; off = 18876416; }
    else if (flat < 19926016) { t = 7; off = 19924992; }
    else if (flat < 20974592) { t = 8; off = 19926016; }
    else                      { t = 9; off = 20974592; }
    const long li = flat - off;
    if (f32) {
      const float* s = (const float*)a.src[t] + li;
      const f32x4 lo = *(const f32x4*)s;
      const f32x4 hi = *(const f32x4*)(s + 4);
      ushort8 o;
      o[0] = f2b(lo[0]); o[1] = f2b(lo[1]); o[2] = f2b(lo[2]); o[3] = f2b(lo[3]);
      o[4] = f2b(hi[0]); o[5] = f2b(hi[1]); o[6] = f2b(hi[2]); o[7] = f2b(hi[3]);
      *(ushort8*)(dst + flat) = o;
    } else {
      *(ushort8*)(dst + flat) =
          *(const ushort8*)((const unsigned short*)a.src[t] + li);
    }
  }
}

#define MODE_BIAS 0  // bf16 out = (acc + bias[n])*scale  (vt: V^T store)
#define MODE_RES  2  // bf16 out = acc/denom[row] + res[m,n]
#define MODE_OUT  4  // format-aware out = acc + bias[n]  (fp32 or bf16 store)
#define MODE_PEXP 5  // bf16 out = exp(acc); denom[row] += row-sum

// XCD-band swizzle: round-robin XCD = linear%8 (assumed); blocks sharing a
// logical `by` (same A row-tile) land on one XCD, bx sweeping 0..gx.
// Requires gy % 8 == 0 (true for all our grids).
__device__ __forceinline__ void xcd_swizzle(int gx, int gy, int& bx, int& by) {
  const int L = blockIdx.y * gx + blockIdx.x;
  const int r = L & 7, m = L >> 3;
  bx = m % gx;
  by = r * (gy >> 3) + m / gx;
}

// ===========================================================================
// 128x128 core, BK=64 per barrier, 4 waves (2x2) of 64x64, fp32 accum,
// global_load_lds width=16 staging, mfma_f32_16x16x32_bf16.
// LDS: As/Bs = [128 rows][64 cols] bf16 (128B row stride, 16KB each).
// Swizzle (verified conflicts=0): chunk (row, ch) stored at position
// ch ^ (row&7); staging pre-swizzles the GLOBAL source chunk (LDS dest
// stays linear: thread tid -> bytes tid*16 + issue*4096); fragment reads
// use chk = ((4u+quad) ^ (lrow&7))*8 (row&7 == lrow&7 for all fragment
// rows since 64 and 16 are multiples of 8).
// vt (MODE_BIAS only): store transposed to C as Vt[b][col][kv].
// ===========================================================================
template <int MODE>
__device__ __forceinline__ void gemm_core(
    const unsigned short* __restrict__ A, const unsigned short* __restrict__ B,
    void* __restrict__ C, const unsigned short* __restrict__ bias,
    const unsigned short* __restrict__ Res, const int* __restrict__ flg,
    float* __restrict__ dn, int N, int K, float scale, int bx, int by,
    int vt) {
  __shared__ __align__(16) unsigned short As[128 * 64];
  __shared__ __align__(16) unsigned short Bs[128 * 64];
  const int tid = threadIdx.x;
  const int wave = tid >> 6, lane = tid & 63;
  const int wm = wave >> 1, wn = wave & 1;
  const int quad = lane >> 4, lrow = lane & 15;

  // staging map: thread tid covers linear LDS bytes tid*16 (+4096/issue);
  // logical source chunk is pre-swizzled (involution ch ^ (row&7)).
  const int srow = tid >> 3;                    // 0..31 (issue-0 row)
  const int sch = (tid & 7) ^ (srow & 7);       // swizzled source chunk
  const unsigned short* ag = A + (long)(by * 128 + srow) * K + sch * 8;
  const unsigned short* bg = B + (long)(bx * 128 + srow) * K + sch * 8;
  char* const lA = (char*)As + tid * 16;
  char* const lB = (char*)Bs + tid * 16;

  f32x4 acc[4][4];
#pragma unroll
  for (int i = 0; i < 4; ++i)
#pragma unroll
    for (int j = 0; j < 4; ++j) acc[i][j] = (f32x4){0.f, 0.f, 0.f, 0.f};

  for (int kt = 0; kt < K; kt += 64) {
#pragma unroll
    for (int s = 0; s < 4; ++s) {   // 4 issues x 32 rows = 128 rows
      async_copy16(ag + kt + (long)32 * s * K, lA + s * 4096);
      async_copy16(bg + kt + (long)32 * s * K, lB + s * 4096);
    }
    __syncthreads();
#pragma unroll
    for (int u = 0; u < 2; ++u) {
      const int chk = ((4 * u + quad) ^ (lrow & 7)) * 8;
      short8 af[4], bfr[4];
#pragma unroll
      for (int i = 0; i < 4; ++i)
        af[i] = *(const short8*)(As + (wm * 64 + i * 16 + lrow) * 64 + chk);
#pragma unroll
      for (int j = 0; j < 4; ++j)
        bfr[j] = *(const short8*)(Bs + (wn * 64 + j * 16 + lrow) * 64 + chk);
#pragma unroll
      for (int i = 0; i < 4; ++i)
#pragma unroll
        for (int j = 0; j < 4; ++j)
          acc[i][j] = __builtin_amdgcn_mfma_f32_16x16x32_bf16(
              af[i], bfr[j], acc[i][j], 0, 0, 0);
    }
    __syncthreads();
  }

  // C/D layout: col=lane&15, row=(lane>>4)*4+reg (m89-verified)

  if (MODE == MODE_PEXP) {
    // store P = bf16(exp(acc)) (scale baked into Q) and accumulate per-row
    // sums of the ROUNDED p into dn[row] (what PV will actually consume).
#pragma unroll
    for (int i = 0; i < 4; ++i) {
      const long row = (long)by * 128 + wm * 64 + i * 16 + quad * 4;
#pragma unroll
      for (int r = 0; r < 4; ++r) {
        float rs = 0.f;
#pragma unroll
        for (int j = 0; j < 4; ++j) {
          const long col = (long)bx * 128 + wn * 64 + j * 16 + lrow;
          const unsigned short pb = f2b(__expf(acc[i][j][r]));
          ((unsigned short*)C)[(row + r) * N + col] = pb;
          rs += b2f(pb);
        }
        rs += __shfl_xor(rs, 1);
        rs += __shfl_xor(rs, 2);
        rs += __shfl_xor(rs, 4);
        rs += __shfl_xor(rs, 8);
        if (lrow == 0) atomicAdd(&dn[row + r], rs);
      }
    }
    return;
  }

  const bool f32out = (MODE == MODE_OUT) ? (*flg != 0) : false;
#pragma unroll
  for (int i = 0; i < 4; ++i) {
    const long row = (long)by * 128 + wm * 64 + i * 16 + quad * 4;
    float invd[4];
    if (MODE == MODE_RES) {
#pragma unroll
      for (int r = 0; r < 4; ++r) invd[r] = 1.0f / dn[row + r];
    }
#pragma unroll
    for (int j = 0; j < 4; ++j) {
      const long col = (long)bx * 128 + wn * 64 + j * 16 + lrow;
      if (MODE == MODE_BIAS && vt) {
        // V^T store: Vt[b][col][kv], 4 consecutive rows -> one 8B store
        const float bb = b2f(bias[col]);
        ushort4v pk;
#pragma unroll
        for (int r = 0; r < 4; ++r) pk[r] = f2b((acc[i][j][r] + bb) * scale);
        const long b = row >> 11, kvr = row & 2047;
        *(ushort4v*)((unsigned short*)C + b * 2097152 + col * 2048 + kvr) = pk;
        continue;
      }
#pragma unroll
      for (int r = 0; r < 4; ++r) {
        const float v = acc[i][j][r];
        const long idx = (row + r) * N + col;
        if (MODE == MODE_BIAS) {
          ((unsigned short*)C)[idx] = f2b((v + b2f(bias[col])) * scale);
        } else if (MODE == MODE_RES) {
          ((unsigned short*)C)[idx] = f2b(v * invd[r] + b2f(Res[idx]));
        } else {  // MODE_OUT
          const float o = v + b2f(bias[col]);
          if (f32out) ((float*)C)[idx] = o;
          else        ((unsigned short*)C)[idx] = f2b(o);
        }
      }
    }
  }
}

template <int MODE>
__global__ __launch_bounds__(256, 4) void gemm_nt(
    const unsigned short* __restrict__ A, const unsigned short* __restrict__ B,
    void* __restrict__ C, const unsigned short* __restrict__ bias,
    const unsigned short* __restrict__ Res, const int* __restrict__ flg,
    float* __restrict__ dn, int N, int K, float scale, long sA, long sB,
    long sC, long sR, int vt) {
  const int bz = blockIdx.z;
  int bx, by;
  xcd_swizzle(gridDim.x, gridDim.y, bx, by);
  const unsigned short* Rb = (MODE == MODE_RES) ? Res + bz * sR : nullptr;
  float* dnb = (MODE == MODE_RES || MODE == MODE_PEXP) ? dn + bz * 2048
                                                       : nullptr;
  void* Cb = (MODE == MODE_OUT) ? (void*)((char*)C)
                                : (void*)((unsigned short*)C + bz * sC);
  gemm_core<MODE>(A + bz * sA, B + bz * sB, Cb, bias, Rb, flg, dnb, N, K,
                  scale, bx, by, vt);
}

// merged Q/K/V projections: blockIdx.z selects (A,B,C,bias); z==0 (Q)
// carries the softmax scale (2^-5, exact exponent shift -> S bit-identical);
// z==2 (V) stores transposed into the Vt buffer.
struct QkvArgs {
  const unsigned short* A[3];
  const unsigned short* B[3];
  unsigned short* C[3];
  const unsigned short* bias[3];
};
__global__ __launch_bounds__(256, 4) void gemm_qkv(QkvArgs a, int N, int K,
                                                   float qscale) {
  const int z = blockIdx.z;
  int bx, by;
  xcd_swizzle(gridDim.x, gridDim.y, bx, by);
  gemm_core<MODE_BIAS>(a.A[z], a.B[z], a.C[z], a.bias[z], nullptr, nullptr,
                       nullptr, N, K, z == 0 ? qscale : 1.f, bx, by,
                       z == 2 ? 1 : 0);
}

extern "C" void kernel_launch(void* const* d_in, const int* in_sizes, int n_in,
                              void* d_out, int out_size, void* d_ws,
                              size_t ws_size, hipStream_t stream) {
  char* ws = (char*)d_ws;
  const long MB = 1 << 20;
  unsigned short* C0  = (unsigned short*)ws;  // bf16 concat of inputs
  unsigned short* xb  = C0;
  unsigned short* ceb = C0 + 8388608;
  unsigned short* Wqb = C0 + 16777216;
  unsigned short* bqb = C0 + 17825792;
  unsigned short* Wkb = C0 + 17826816;
  unsigned short* bkb = C0 + 18875392;
  unsigned short* Wvb = C0 + 18876416;
  unsigned short* bvb = C0 + 19924992;
  unsigned short* Wob = C0 + 19926016;
  unsigned short* bob = C0 + 20974592;
  int*            flg = (int*)(ws + 41 * MB);
  unsigned short* Q   = (unsigned short*)(ws + 42 * MB);  // 42-58
  unsigned short* Kp  = (unsigned short*)(ws + 58 * MB);  // 58-74
  unsigned short* Vt  = (unsigned short*)(ws + 74 * MB);  // 74-90 (V^T direct)
  unsigned short* S   = (unsigned short*)(ws + 90 * MB);  // 90-122 (->P=exp)
  float*          dnm = (float*)(ws + 122 * MB);          // 4x2048 f32 denom
  unsigned short* Ar  = Kp;  // reuse K slot after QK^T

  const dim3 blk(256);
  const float scale = 0.03125f;  // 1/sqrt(1024) = 2^-5 (exact in bf16 mul)

  // convert + self-detect + flag publish + denom zero (one dispatch)
  CvtArgs ca;
  for (int i = 0; i < 10; ++i) ca.src[i] = d_in[i];
  convert_all<<<dim3(2048), blk, 0, stream>>>(ca, C0, flg, dnm);

  // merged QKV projections: M=8192 (batch folded), N=K=1024; Q carries the
  // softmax scale; V transposed into Vt ([b][1024][2048]).  Grid 8x64x3.
  QkvArgs qa;
  qa.A[0] = xb;  qa.A[1] = ceb; qa.A[2] = ceb;
  qa.B[0] = Wqb; qa.B[1] = Wkb; qa.B[2] = Wvb;
  qa.C[0] = Q;   qa.C[1] = Kp;  qa.C[2] = Vt;
  qa.bias[0] = bqb; qa.bias[1] = bkb; qa.bias[2] = bvb;
  gemm_qkv<<<dim3(8, 64, 3), blk, 0, stream>>>(qa, 1024, 1024, scale);

  // P = exp(QK^T) unnormalized (bf16; scale already in Q) + per-row denom
  // accumulation; per batch 2048x2048, K=1024.
  gemm_nt<MODE_PEXP><<<dim3(16, 16, 4), blk, 0, stream>>>(
      Q, Kp, S, nullptr, nullptr, nullptr, dnm, 2048, 1024, 1.f,
      2048L * 1024, 2048L * 1024, 2048L * 2048, 0, 0);

  // A = x + (P@V)/denom : per batch M=2048, N=1024, K=2048 (B=Vt, NT)
  gemm_nt<MODE_RES><<<dim3(8, 16, 4), blk, 0, stream>>>(
      S, Vt, Ar, nullptr, xb, nullptr, dnm, 1024, 2048, 1.f,
      2048L * 2048, 1024L * 2048, 2048L * 1024, 2048L * 1024, 0);

  // out = A@Wo^T + bo, written straight to d_out in detected format
  gemm_nt<MODE_OUT><<<dim3(8, 64, 1), blk, 0, stream>>>(
      Ar, Wob, d_out, bob, nullptr, flg, nullptr, 1024, 1024, 1.f,
      0, 0, 0, 0, 0);
}